// Round 13
// baseline (3735.354 us; speedup 1.0000x reference)
//
#include <hip/hip_runtime.h>
#include <hip/hip_bf16.h>
#include <stdint.h>

typedef unsigned short u16;
typedef unsigned int   u32;
typedef unsigned long long u64;

#define B_    8
#define N_    8192
#define M_    2048
#define NS_   32
#define CIN_  64
#define ROWS_ (B_*M_*NS_)          // 524288
#define BIGF  1e10f
#define EPSF  1e-5f
#define INV_ROWS (1.0f/524288.0f)  // 2^-19, exact

__device__ __forceinline__ u16 f2bf(float f){
  u32 x=__float_as_uint(f);
  return (u16)((x + 0x7FFFu + ((x>>16)&1u))>>16);   // RNE
}
__device__ __forceinline__ float bf2f(u16 u){ return __uint_as_float(((u32)u)<<16); }

// ---------------------------------------------------------------- prep (fp32 weights in)
__global__ __launch_bounds__(256) void k_prep(
    const float* w0,const float* b0,const float* g0,const float* bt0,
    const float* w1,const float* b1,const float* g1,const float* bt1,
    const float* w2,const float* b2,const float* g2,const float* bt2,
    float* Wt0,float* Wt1,float* Wt2,
    float* biasf,float* gf,float* btf,float* stats)
{
  int tid=threadIdx.x;
  for (int i=tid;i<768;i+=256) stats[i]=0.f;
  for (int i=tid;i<67*64;i+=256){ int c=i>>6,o=i&63;  Wt0[c*64+o]=w0[o*67+c]; }
  for (int i=tid;i<64*64;i+=256){ int c=i>>6,o=i&63;  Wt1[c*64+o]=w1[o*64+c]; }
  for (int i=tid;i<64*128;i+=256){int c=i>>7,o=i&127; Wt2[c*128+o]=w2[o*64+c]; }
  if (tid<64){
    biasf[0*128+tid]=b0[tid]; gf[0*128+tid]=g0[tid]; btf[0*128+tid]=bt0[tid];
    biasf[1*128+tid]=b1[tid]; gf[1*128+tid]=g1[tid]; btf[1*128+tid]=bt1[tid];
  }
  if (tid<128){
    biasf[2*128+tid]=b2[tid]; gf[2*128+tid]=g2[tid]; btf[2*128+tid]=bt2[tid];
  }
}

// ------------------------------------------------------- feature transpose
__global__ __launch_bounds__(256) void k_tr(const float* __restrict__ feats, u16* __restrict__ featT)
{
  __shared__ float t[64][65];
  int bb=blockIdx.y, n0=blockIdx.x*64, tid=threadIdx.x;
  int a=tid&63, q=tid>>6;
  const float* fp = feats + (size_t)bb*CIN_*N_;
  #pragma unroll
  for (int s=0;s<16;s++){ int c=q*16+s; t[c][a]=fp[(size_t)c*N_ + n0 + a]; }
  __syncthreads();
  u16* op = featT + (size_t)bb*N_*CIN_;
  #pragma unroll
  for (int s=0;s<16;s++){ int n=q*16+s; op[(size_t)(n0+n)*CIN_ + a] = f2bf(t[a][n]); }
}

// ---------------------------------------------------------------- FPS
// 1024 threads = 16 waves (4/SIMD for latency hiding), 8 pts/thread register-resident.
// Selection semantics identical to R10-R12 passing kernels: PRE-update emission,
// exact f32 no-FMA distances, first-max argmax with lowest-index ties — expressed
// as max over packed keys (f32bits(dist)<<32 | (0xFFFFFFFF - idx)). ONE barrier/step,
// parity-double-buffered per-wave key publish; final merge = lane loads skey[lane&15]
// + 4-level shfl_xor(width 16) butterfly so every thread holds the global max key.
__global__ __launch_bounds__(1024) void k_fps(const float* __restrict__ xyz,
                                              float* __restrict__ nxyz, float* __restrict__ out0)
{
  __shared__ float sx[N_], sy[N_], sz[N_];
  __shared__ int sidx[M_];
  __shared__ u64 skey[2][16];
  int b=blockIdx.x, tid=threadIdx.x;
  const float* xp = xyz + (size_t)b*N_*3;
  for (int i=tid;i<N_;i+=1024){ sx[i]=xp[i*3]; sy[i]=xp[i*3+1]; sz[i]=xp[i*3+2]; }
  __syncthreads();
  float px[8],py[8],pz[8],md[8];
  int base = tid*8;
  #pragma unroll
  for (int j=0;j<8;j++){ px[j]=sx[base+j]; py[j]=sy[base+j]; pz[j]=sz[base+j]; md[j]=BIGF; }
  int far=0;
  int lane=tid&63, wv=tid>>6;
  for (int step=0; step<M_; step++){
    if (tid==0) sidx[step]=far;          // PRE-update emission
    float cx=sx[far], cy=sy[far], cz=sz[far];
    u64 kb=0;
    #pragma unroll
    for (int j=0;j<8;j++){
      float dx=__fsub_rn(px[j],cx), dy=__fsub_rn(py[j],cy), dz=__fsub_rn(pz[j],cz);
      float d = __fmul_rn(dx,dx);
      d = __fadd_rn(d, __fmul_rn(dy,dy));
      d = __fadd_rn(d, __fmul_rn(dz,dz));
      float m = fminf(md[j], d); md[j]=m;
      u64 k = ((u64)__float_as_uint(m)<<32) | (u64)(0xFFFFFFFFu - (u32)(base+j));
      kb = (k>kb) ? k : kb;              // max key == (max dist, min idx)
    }
    #pragma unroll
    for (int off=32; off>0; off>>=1){
      u64 o = __shfl_down(kb, off);
      kb = (o>kb) ? o : kb;
    }
    int par = step & 1;
    if (lane==0) skey[par][wv]=kb;
    __syncthreads();                     // single barrier per step
    u64 km = skey[par][lane & 15];
    #pragma unroll
    for (int off=1; off<16; off<<=1){
      u64 o = __shfl_xor(km, off, 16);
      km = (o>km) ? o : km;
    }
    far = (int)(0xFFFFFFFFu - (u32)(km & 0xFFFFFFFFull));
  }
  // f32 output: exact raw coordinates of selected points
  for (int i=tid;i<M_;i+=1024){
    int id = sidx[i];
    float x=sx[id], y=sy[id], z=sz[id];
    size_t o=(size_t)(b*M_+i)*3;
    nxyz[o]=x; nxyz[o+1]=y; nxyz[o+2]=z;
    out0[o]=x; out0[o+1]=y; out0[o+2]=z;
  }
}

// ---------------------------------------------------------------- ball query
#define BQCAP 512
__global__ __launch_bounds__(512) void k_bq(const float* __restrict__ xyz, const float* __restrict__ nxyz,
                                            int* __restrict__ knn)
{
  __shared__ float4 sP[N_];
  __shared__ float candd[8][BQCAP];
  __shared__ u16  candi[8][BQCAP];
  int tid=threadIdx.x;
  int cid0 = blockIdx.x*8;
  int b = cid0 >> 11;
  const float* xp = xyz + (size_t)b*N_*3;
  for (int i=tid;i<N_;i+=512){
    float x=xp[i*3], y=xp[i*3+1], z=xp[i*3+2];
    float x2 = __fmul_rn(x,x);
    x2 = __fadd_rn(x2, __fmul_rn(y,y));
    x2 = __fadd_rn(x2, __fmul_rn(z,z));
    sP[i]=make_float4(x,y,z,x2);
  }
  __syncthreads();
  int w=tid>>6, lane=tid&63;
  int cid = cid0 + w;
  float cx=nxyz[(size_t)cid*3], cy=nxyz[(size_t)cid*3+1], cz=nxyz[(size_t)cid*3+2];
  float c2 = __fmul_rn(cx,cx);
  c2 = __fadd_rn(c2, __fmul_rn(cy,cy));
  c2 = __fadd_rn(c2, __fmul_rn(cz,cz));
  int cnt=0;
  for (int i0=0;i0<N_;i0+=64){
    int i=i0+lane;
    float4 p=sP[i];
    float dot = __fmul_rn(cx,p.x);
    dot = __fadd_rn(dot, __fmul_rn(cy,p.y));
    dot = __fadd_rn(dot, __fmul_rn(cz,p.z));
    float d2 = __fsub_rn(__fadd_rn(c2,p.w), __fmul_rn(2.0f,dot));
    float d = sqrtf(fmaxf(d2,0.f));
    bool in = (d <= 0.4f);
    u64 msk = __ballot(in);
    int pos = cnt + __popcll(msk & ((1ull<<lane)-1ull));
    if (in && pos<BQCAP){ candd[w][pos]=d; candi[w][pos]=(u16)i; }
    cnt += __popcll(msk);
  }
  int R = cnt<BQCAP ? cnt : BQCAP;
  int* kout = knn + (size_t)cid*NS_;
  if (R >= NS_){
    for (int s=0;s<NS_;s++){
      float bvv=3e38f; int bpp=1<<30;
      for (int j=lane;j<R;j+=64){
        float v=candd[w][j];
        if (v<bvv){ bvv=v; bpp=j; }
      }
      #pragma unroll
      for (int off=32;off>0;off>>=1){
        float ov=__shfl_down(bvv,off); int op=__shfl_down(bpp,off);
        if (ov<bvv || (ov==bvv && op<bpp)){ bvv=ov; bpp=op; }
      }
      if (lane==0){ kout[s]=candi[w][bpp]; candd[w][bpp]=3e38f; }
    }
  } else {
    if (lane<R) kout[lane]=candi[w][lane];
    int need = NS_-R, slot = R;
    for (int i0=0; i0<N_ && need>0; i0+=64){
      int i=i0+lane;
      float4 p=sP[i];
      float dot = __fmul_rn(cx,p.x);
      dot = __fadd_rn(dot, __fmul_rn(cy,p.y));
      dot = __fadd_rn(dot, __fmul_rn(cz,p.z));
      float d2 = __fsub_rn(__fadd_rn(c2,p.w), __fmul_rn(2.0f,dot));
      float d = sqrtf(fmaxf(d2,0.f));
      bool in = (d <= 0.4f);
      u64 mm = __ballot(!in);
      while (mm && need>0){
        int bpos = __ffsll((long long)mm)-1;
        if (lane==0) kout[slot] = i0+bpos;
        slot++; need--;
        mm &= mm-1;
      }
    }
  }
}

// ---------------------------------------------------------------- layer 0 (gather+concat fused)
__global__ __launch_bounds__(256) void k_mm0(const float* __restrict__ xyz, const u16* __restrict__ featT,
                                             const int* __restrict__ knn, const float* __restrict__ nxyz,
                                             const float* __restrict__ Wt0, const float* __restrict__ biasf,
                                             u16* __restrict__ Y0)
{
  __shared__ u16 Xs[256*70];
  __shared__ float Wl[67*64];
  int tid=threadIdx.x;
  for (int i=tid;i<67*64;i+=256) Wl[i]=Wt0[i];
  int base = blockIdx.x*256;
  {
    int row = base + tid;
    int bm  = row >> 5;
    int b   = row >> 16;
    int n   = knn[row];
    const float* cp = nxyz + (size_t)bm*3;
    const float* xp = xyz + ((size_t)b*N_ + n)*3;
    u16* xr = &Xs[tid*70];
    xr[0]=f2bf(xp[0]-cp[0]);
    xr[1]=f2bf(xp[1]-cp[1]);
    xr[2]=f2bf(xp[2]-cp[2]);
    const uint4* fp = (const uint4*)(featT + ((size_t)b*N_ + n)*CIN_);
    #pragma unroll
    for (int i=0;i<8;i++){
      uint4 v=fp[i];
      u16* d = xr + 3 + i*8;
      d[0]=(u16)(v.x&0xFFFFu); d[1]=(u16)(v.x>>16);
      d[2]=(u16)(v.y&0xFFFFu); d[3]=(u16)(v.y>>16);
      d[4]=(u16)(v.z&0xFFFFu); d[5]=(u16)(v.z>>16);
      d[6]=(u16)(v.w&0xFFFFu); d[7]=(u16)(v.w>>16);
    }
  }
  __syncthreads();
  int g=tid>>7, rt=tid&127;
  float acc0[32], acc1[32];
  #pragma unroll
  for (int j=0;j<32;j++){ acc0[j]=0.f; acc1[j]=0.f; }
  const u16* xa=&Xs[rt*70];
  const u16* xb=&Xs[(rt+128)*70];
  for (int c=0;c<67;c++){
    float a=bf2f(xa[c]);
    float bx=bf2f(xb[c]);
    const float4* wr=(const float4*)&Wl[c*64 + g*32];
    #pragma unroll
    for (int o=0;o<8;o++){
      float4 wv=wr[o];
      acc0[o*4+0]+=a*wv.x;  acc0[o*4+1]+=a*wv.y;  acc0[o*4+2]+=a*wv.z;  acc0[o*4+3]+=a*wv.w;
      acc1[o*4+0]+=bx*wv.x; acc1[o*4+1]+=bx*wv.y; acc1[o*4+2]+=bx*wv.z; acc1[o*4+3]+=bx*wv.w;
    }
  }
  float bb[32];
  #pragma unroll
  for (int j=0;j<32;j++) bb[j]=biasf[g*32+j];
  u16* y0p = Y0 + ((size_t)(base+rt))*64 + g*32;
  u16* y1p = Y0 + ((size_t)(base+rt+128))*64 + g*32;
  #pragma unroll
  for (int j=0;j<32;j++){
    y0p[j]=f2bf(acc0[j]+bb[j]);
    y1p[j]=f2bf(acc1[j]+bb[j]);
  }
}

// ---------------------------------------------------------------- channel stats (sum, sumsq)
template<int C>
__global__ __launch_bounds__(256) void k_stats(const u16* __restrict__ Y, float* __restrict__ statsOut)
{
  __shared__ float red[512];
  int tid=threadIdx.x;
  int c = tid & (C-1);
  int gp = tid / C;
  const int GPT = 256/C;
  int r0 = blockIdx.x*GPT + gp;
  int stride = gridDim.x*GPT;
  float s=0.f, ss=0.f;
  for (int r=r0; r<ROWS_; r+=stride){
    float v=bf2f(Y[(size_t)r*C + c]);
    s+=v; ss+=v*v;
  }
  red[tid*2]=s; red[tid*2+1]=ss;
  __syncthreads();
  if (tid<C){
    float a=0.f,b2=0.f;
    for (int q=0;q<GPT;q++){ a+=red[(q*C+tid)*2]; b2+=red[(q*C+tid)*2+1]; }
    atomicAdd(&statsOut[tid*2],a);
    atomicAdd(&statsOut[tid*2+1],b2);
  }
}

// ---------------------------------------------------------------- layer 1 (bn0+relu fused into stage; in-place)
__global__ __launch_bounds__(256) void k_mm1(u16* __restrict__ Y, const float* __restrict__ Wt1,
                                             const float* __restrict__ bias1, const float* __restrict__ gf0,
                                             const float* __restrict__ btf0, const float* __restrict__ stats0)
{
  __shared__ u16 Xs[256*66];
  __shared__ float Wl[64*64];
  __shared__ float sc[64], sh[64];
  int tid=threadIdx.x;
  if (tid<64){
    float mu = stats0[tid*2]*INV_ROWS;
    float var= stats0[tid*2+1]*INV_ROWS - mu*mu;
    float rs = 1.0f/sqrtf(var+EPSF);
    float s  = rs*gf0[tid];
    sc[tid]=s; sh[tid]=btf0[tid]-mu*s;
  }
  for (int i=tid;i<64*64;i+=256) Wl[i]=Wt1[i];
  __syncthreads();
  size_t base=(size_t)blockIdx.x*256;
  for (int i=tid;i<2048;i+=256){
    int rl=i>>3, c0=(i&7)*8;
    uint4 v=*(const uint4*)(Y + (base+rl)*64 + c0);
    u32 arr[4]={v.x,v.y,v.z,v.w};
    u16* d=&Xs[rl*66+c0];
    #pragma unroll
    for (int q=0;q<4;q++){
      int cc=c0+q*2;
      float lo=bf2f((u16)(arr[q]&0xFFFFu));
      float hi=bf2f((u16)(arr[q]>>16));
      lo=fmaxf(0.f, lo*sc[cc]+sh[cc]);
      hi=fmaxf(0.f, hi*sc[cc+1]+sh[cc+1]);
      d[q*2]=f2bf(lo); d[q*2+1]=f2bf(hi);
    }
  }
  __syncthreads();
  int g=tid>>7, rt=tid&127;
  float acc0[32], acc1[32];
  #pragma unroll
  for (int j=0;j<32;j++){ acc0[j]=0.f; acc1[j]=0.f; }
  const u16* xa=&Xs[rt*66];
  const u16* xb=&Xs[(rt+128)*66];
  for (int c=0;c<64;c++){
    float a=bf2f(xa[c]);
    float bx=bf2f(xb[c]);
    const float4* wr=(const float4*)&Wl[c*64 + g*32];
    #pragma unroll
    for (int o=0;o<8;o++){
      float4 wv=wr[o];
      acc0[o*4+0]+=a*wv.x;  acc0[o*4+1]+=a*wv.y;  acc0[o*4+2]+=a*wv.z;  acc0[o*4+3]+=a*wv.w;
      acc1[o*4+0]+=bx*wv.x; acc1[o*4+1]+=bx*wv.y; acc1[o*4+2]+=bx*wv.z; acc1[o*4+3]+=bx*wv.w;
    }
  }
  float bb[32];
  #pragma unroll
  for (int j=0;j<32;j++) bb[j]=bias1[g*32+j];
  u16* y0p = Y + (base+rt)*64 + g*32;
  u16* y1p = Y + (base+rt+128)*64 + g*32;
  #pragma unroll
  for (int j=0;j<32;j++){
    y0p[j]=f2bf(acc0[j]+bb[j]);
    y1p[j]=f2bf(acc1[j]+bb[j]);
  }
}

// ---------------------------------------------------------------- layer 2 pass A: stats only (Y2 never stored)
__global__ __launch_bounds__(256) void k_mm2a(const u16* __restrict__ Y1, const float* __restrict__ Wt2,
                                              const float* __restrict__ bias2, const float* __restrict__ gf1,
                                              const float* __restrict__ btf1, const float* __restrict__ stats1,
                                              float* __restrict__ stats2)
{
  __shared__ u16 Xs[128*66];
  __shared__ float Wl[64*128];
  __shared__ float sc[64], sh[64];
  int tid=threadIdx.x;
  if (tid<64){
    float mu = stats1[tid*2]*INV_ROWS;
    float var= stats1[tid*2+1]*INV_ROWS - mu*mu;
    float rs = 1.0f/sqrtf(var+EPSF);
    float s  = rs*gf1[tid];
    sc[tid]=s; sh[tid]=btf1[tid]-mu*s;
  }
  for (int i=tid;i<64*128;i+=256) Wl[i]=Wt2[i];
  int g=tid>>6, rt=tid&63;
  float bb[32];
  #pragma unroll
  for (int j=0;j<32;j++) bb[j]=bias2[g*32+j];
  float sSum[32], sSq[32];
  #pragma unroll
  for (int j=0;j<32;j++){ sSum[j]=0.f; sSq[j]=0.f; }
  __syncthreads();
  for (int tile=blockIdx.x; tile<4096; tile+=gridDim.x){
    size_t base=(size_t)tile*128;
    for (int i=tid;i<1024;i+=256){
      int rl=i>>3, c0=(i&7)*8;
      uint4 v=*(const uint4*)(Y1 + (base+rl)*64 + c0);
      u32 arr[4]={v.x,v.y,v.z,v.w};
      u16* d=&Xs[rl*66+c0];
      #pragma unroll
      for (int q=0;q<4;q++){
        int cc=c0+q*2;
        float lo=bf2f((u16)(arr[q]&0xFFFFu));
        float hi=bf2f((u16)(arr[q]>>16));
        lo=fmaxf(0.f, lo*sc[cc]+sh[cc]);
        hi=fmaxf(0.f, hi*sc[cc+1]+sh[cc+1]);
        d[q*2]=f2bf(lo); d[q*2+1]=f2bf(hi);
      }
    }
    __syncthreads();
    float acc0[32], acc1[32];
    #pragma unroll
    for (int j=0;j<32;j++){ acc0[j]=0.f; acc1[j]=0.f; }
    const u16* xa=&Xs[rt*66];
    const u16* xb=&Xs[(rt+64)*66];
    for (int c=0;c<64;c++){
      float a=bf2f(xa[c]);
      float bx=bf2f(xb[c]);
      const float4* wr=(const float4*)&Wl[c*128 + g*32];
      #pragma unroll
      for (int o=0;o<8;o++){
        float4 wv=wr[o];
        acc0[o*4+0]+=a*wv.x;  acc0[o*4+1]+=a*wv.y;  acc0[o*4+2]+=a*wv.z;  acc0[o*4+3]+=a*wv.w;
        acc1[o*4+0]+=bx*wv.x; acc1[o*4+1]+=bx*wv.y; acc1[o*4+2]+=bx*wv.z; acc1[o*4+3]+=bx*wv.w;
      }
    }
    #pragma unroll
    for (int j=0;j<32;j++){
      float y0=acc0[j]+bb[j], y1=acc1[j]+bb[j];
      sSum[j]+=y0+y1;
      sSq[j] +=y0*y0+y1*y1;
    }
    __syncthreads();
  }
  #pragma unroll
  for (int off=32;off>0;off>>=1){
    #pragma unroll
    for (int j=0;j<32;j++){
      sSum[j]+=__shfl_down(sSum[j],off);
      sSq[j] +=__shfl_down(sSq[j],off);
    }
  }
  if (rt==0){
    #pragma unroll
    for (int j=0;j<32;j++){
      atomicAdd(&stats2[(g*32+j)*2],  sSum[j]);
      atomicAdd(&stats2[(g*32+j)*2+1],sSq[j]);
    }
  }
}

// ---------------------------------------------------------------- layer 2 pass B: recompute + bn2 + relu + maxpool -> out1 (f32)
__global__ __launch_bounds__(256) void k_mm2b(const u16* __restrict__ Y1, const float* __restrict__ Wt2,
                                              const float* __restrict__ bias2, const float* __restrict__ gf1,
                                              const float* __restrict__ btf1, const float* __restrict__ stats1,
                                              const float* __restrict__ gf2, const float* __restrict__ btf2,
                                              const float* __restrict__ stats2, float* __restrict__ out1)
{
  __shared__ u16 Xs[128*66];
  __shared__ float Wl[64*128];
  __shared__ float sc1[64], sh1[64], sc2[128], sh2[128];
  __shared__ float res[4][128];
  int tid=threadIdx.x;
  if (tid<64){
    float mu = stats1[tid*2]*INV_ROWS;
    float var= stats1[tid*2+1]*INV_ROWS - mu*mu;
    float rs = 1.0f/sqrtf(var+EPSF);
    float s  = rs*gf1[tid];
    sc1[tid]=s; sh1[tid]=btf1[tid]-mu*s;
  }
  if (tid<128){
    float mu = stats2[tid*2]*INV_ROWS;
    float var= stats2[tid*2+1]*INV_ROWS - mu*mu;
    float rs = 1.0f/sqrtf(var+EPSF);
    float s  = rs*gf2[tid];
    sc2[tid]=s; sh2[tid]=btf2[tid]-mu*s;
  }
  for (int i=tid;i<64*128;i+=256) Wl[i]=Wt2[i];
  int g=tid>>6, rt=tid&63;
  float bb[32];
  #pragma unroll
  for (int j=0;j<32;j++) bb[j]=bias2[g*32+j];
  __syncthreads();
  size_t base=(size_t)blockIdx.x*128;
  for (int i=tid;i<1024;i+=256){
    int rl=i>>3, c0=(i&7)*8;
    uint4 v=*(const uint4*)(Y1 + (base+rl)*64 + c0);
    u32 arr[4]={v.x,v.y,v.z,v.w};
    u16* d=&Xs[rl*66+c0];
    #pragma unroll
    for (int q=0;q<4;q++){
      int cc=c0+q*2;
      float lo=bf2f((u16)(arr[q]&0xFFFFu));
      float hi=bf2f((u16)(arr[q]>>16));
      lo=fmaxf(0.f, lo*sc1[cc]+sh1[cc]);
      hi=fmaxf(0.f, hi*sc1[cc+1]+sh1[cc+1]);
      d[q*2]=f2bf(lo); d[q*2+1]=f2bf(hi);
    }
  }
  __syncthreads();
  float acc0[32], acc1[32];
  #pragma unroll
  for (int j=0;j<32;j++){ acc0[j]=0.f; acc1[j]=0.f; }
  const u16* xa=&Xs[rt*66];
  const u16* xb=&Xs[(rt+64)*66];
  for (int c=0;c<64;c++){
    float a=bf2f(xa[c]);
    float bx=bf2f(xb[c]);
    const float4* wr=(const float4*)&Wl[c*128 + g*32];
    #pragma unroll
    for (int o=0;o<8;o++){
      float4 wv=wr[o];
      acc0[o*4+0]+=a*wv.x;  acc0[o*4+1]+=a*wv.y;  acc0[o*4+2]+=a*wv.z;  acc0[o*4+3]+=a*wv.w;
      acc1[o*4+0]+=bx*wv.x; acc1[o*4+1]+=bx*wv.y; acc1[o*4+2]+=bx*wv.z; acc1[o*4+3]+=bx*wv.w;
    }
  }
  #pragma unroll
  for (int j=0;j<32;j++){
    int o=g*32+j;
    float a = fmaxf(0.f, (acc0[j]+bb[j])*sc2[o]+sh2[o]);
    float b2= fmaxf(0.f, (acc1[j]+bb[j])*sc2[o]+sh2[o]);
    #pragma unroll
    for (int off=16;off>0;off>>=1){
      a = fmaxf(a, __shfl_down(a, off, 32));
      b2= fmaxf(b2,__shfl_down(b2,off, 32));
    }
    if ((rt&31)==0){
      res[rt>>5][o]     = a;
      res[2+(rt>>5)][o] = b2;
    }
  }
  __syncthreads();
  int bm0 = blockIdx.x*4;
  for (int e=tid;e<512;e+=256){
    int gr=e>>7, o=e&127;
    int bm=bm0+gr; int b=bm>>11, m=bm&2047;
    out1[((size_t)b*128+o)*M_ + m] = res[gr][o];
  }
}

// ---------------------------------------------------------------- launch
extern "C" void kernel_launch(void* const* d_in, const int* in_sizes, int n_in,
                              void* d_out, int out_size, void* d_ws, size_t ws_size,
                              hipStream_t stream)
{
  (void)in_sizes; (void)n_in; (void)out_size; (void)ws_size;
  const float* xyz =(const float*)d_in[0];
  const float* feat=(const float*)d_in[1];
  const float* w0=(const float*)d_in[2],  *b0=(const float*)d_in[3],  *g0=(const float*)d_in[4],  *bt0=(const float*)d_in[5];
  const float* w1=(const float*)d_in[6],  *b1=(const float*)d_in[7],  *g1=(const float*)d_in[8],  *bt1=(const float*)d_in[9];
  const float* w2=(const float*)d_in[10], *b2=(const float*)d_in[11], *g2=(const float*)d_in[12], *bt2=(const float*)d_in[13];
  float* out0=(float*)d_out;
  float* out1=out0 + (size_t)B_*M_*3;

  char* ws=(char*)d_ws;
  float* nxyz =(float*)(ws);              // 196608 B
  int*   knn  =(int*)  (ws + 262144);     // 2097152
  float* Wt0  =(float*)(ws + 2359296);    // 17408
  float* Wt1  =(float*)(ws + 2376704);    // 16384
  float* Wt2  =(float*)(ws + 2393088);    // 32768
  float* biasf=(float*)(ws + 2425856);    // 1536
  float* gfp  =(float*)(ws + 2427392);    // 1536
  float* btfp =(float*)(ws + 2428928);    // 1536
  float* stats=(float*)(ws + 2430464);    // 3072
  u16*   featT=(u16*)  (ws + 2433536);    // 8388608
  u16*   Y0   =(u16*)  (ws + 10822144);   // 67108864  (total ~78 MB)

  k_prep<<<1,256,0,stream>>>(w0,b0,g0,bt0,w1,b1,g1,bt1,w2,b2,g2,bt2,Wt0,Wt1,Wt2,biasf,gfp,btfp,stats);
  k_tr<<<dim3(128,8),256,0,stream>>>(feat, featT);
  k_fps<<<B_,1024,0,stream>>>(xyz, nxyz, out0);
  k_bq<<<2048,512,0,stream>>>(xyz, nxyz, knn);
  k_mm0<<<2048,256,0,stream>>>(xyz, featT, knn, nxyz, Wt0, biasf+0, Y0);
  k_stats<64><<<512,256,0,stream>>>(Y0, stats+0);
  k_mm1<<<2048,256,0,stream>>>(Y0, Wt1, biasf+128, gfp+0, btfp+0, stats+0);
  k_stats<64><<<512,256,0,stream>>>(Y0, stats+256);
  k_mm2a<<<512,256,0,stream>>>(Y0, Wt2, biasf+256, gfp+128, btfp+128, stats+256, stats+512);
  k_mm2b<<<4096,256,0,stream>>>(Y0, Wt2, biasf+256, gfp+128, btfp+128, stats+256, gfp+256, btfp+256, stats+512, out1);
}

// Round 14
// 3304.867 us; speedup vs baseline: 1.1303x; 1.1303x over previous
//
#include <hip/hip_runtime.h>
#include <hip/hip_bf16.h>
#include <stdint.h>

typedef unsigned short u16;
typedef unsigned int   u32;
typedef unsigned long long u64;

#define B_    8
#define N_    8192
#define M_    2048
#define NS_   32
#define CIN_  64
#define ROWS_ (B_*M_*NS_)          // 524288
#define BIGF  1e10f
#define EPSF  1e-5f
#define INV_ROWS (1.0f/524288.0f)  // 2^-19, exact

__device__ __forceinline__ u16 f2bf(float f){
  u32 x=__float_as_uint(f);
  return (u16)((x + 0x7FFFu + ((x>>16)&1u))>>16);   // RNE
}
__device__ __forceinline__ float bf2f(u16 u){ return __uint_as_float(((u32)u)<<16); }

// ---------------------------------------------------------------- prep (fp32 weights in)
__global__ __launch_bounds__(256) void k_prep(
    const float* w0,const float* b0,const float* g0,const float* bt0,
    const float* w1,const float* b1,const float* g1,const float* bt1,
    const float* w2,const float* b2,const float* g2,const float* bt2,
    float* Wt0,float* Wt1,float* Wt2,
    float* biasf,float* gf,float* btf,float* stats)
{
  int tid=threadIdx.x;
  for (int i=tid;i<768;i+=256) stats[i]=0.f;
  for (int i=tid;i<67*64;i+=256){ int c=i>>6,o=i&63;  Wt0[c*64+o]=w0[o*67+c]; }
  for (int i=tid;i<64*64;i+=256){ int c=i>>6,o=i&63;  Wt1[c*64+o]=w1[o*64+c]; }
  for (int i=tid;i<64*128;i+=256){int c=i>>7,o=i&127; Wt2[c*128+o]=w2[o*64+c]; }
  if (tid<64){
    biasf[0*128+tid]=b0[tid]; gf[0*128+tid]=g0[tid]; btf[0*128+tid]=bt0[tid];
    biasf[1*128+tid]=b1[tid]; gf[1*128+tid]=g1[tid]; btf[1*128+tid]=bt1[tid];
  }
  if (tid<128){
    biasf[2*128+tid]=b2[tid]; gf[2*128+tid]=g2[tid]; btf[2*128+tid]=bt2[tid];
  }
}

// ------------------------------------------------------- feature transpose
__global__ __launch_bounds__(256) void k_tr(const float* __restrict__ feats, u16* __restrict__ featT)
{
  __shared__ float t[64][65];
  int bb=blockIdx.y, n0=blockIdx.x*64, tid=threadIdx.x;
  int a=tid&63, q=tid>>6;
  const float* fp = feats + (size_t)bb*CIN_*N_;
  #pragma unroll
  for (int s=0;s<16;s++){ int c=q*16+s; t[c][a]=fp[(size_t)c*N_ + n0 + a]; }
  __syncthreads();
  u16* op = featT + (size_t)bb*N_*CIN_;
  #pragma unroll
  for (int s=0;s<16;s++){ int n=q*16+s; op[(size_t)(n0+n)*CIN_ + a] = f2bf(t[a][n]); }
}

// ---------------------------------------------------------------- FPS (R12 measured-best config)
// 512 threads = 8 waves (2/SIMD), 16 pts/thread register-resident. PRE-update emission,
// exact f32 no-FMA distances, first-max argmax with lowest-index ties via packed key max
// (f32bits(dist)<<32 | (0xFFFFFFFF - idx)). ONE barrier/step, parity-double-buffered
// per-wave key publish, 8-way serial merge in every thread.
__global__ __launch_bounds__(512) void k_fps(const float* __restrict__ xyz,
                                             float* __restrict__ nxyz, float* __restrict__ out0)
{
  __shared__ float sx[N_], sy[N_], sz[N_];
  __shared__ int sidx[M_];
  __shared__ u64 skey[2][8];
  int b=blockIdx.x, tid=threadIdx.x;
  const float* xp = xyz + (size_t)b*N_*3;
  for (int i=tid;i<N_;i+=512){ sx[i]=xp[i*3]; sy[i]=xp[i*3+1]; sz[i]=xp[i*3+2]; }
  __syncthreads();
  float px[16],py[16],pz[16],md[16];
  int base = tid*16;
  #pragma unroll
  for (int j=0;j<16;j++){ px[j]=sx[base+j]; py[j]=sy[base+j]; pz[j]=sz[base+j]; md[j]=BIGF; }
  int far=0;
  int lane=tid&63, wv=tid>>6;
  for (int step=0; step<M_; step++){
    if (tid==0) sidx[step]=far;          // PRE-update emission
    float cx=sx[far], cy=sy[far], cz=sz[far];
    u64 kb=0;
    #pragma unroll
    for (int j=0;j<16;j++){
      float dx=__fsub_rn(px[j],cx), dy=__fsub_rn(py[j],cy), dz=__fsub_rn(pz[j],cz);
      float d = __fmul_rn(dx,dx);
      d = __fadd_rn(d, __fmul_rn(dy,dy));
      d = __fadd_rn(d, __fmul_rn(dz,dz));
      float m = fminf(md[j], d); md[j]=m;
      u64 k = ((u64)__float_as_uint(m)<<32) | (u64)(0xFFFFFFFFu - (u32)(base+j));
      kb = (k>kb) ? k : kb;              // max key == (max dist, min idx)
    }
    #pragma unroll
    for (int off=32; off>0; off>>=1){
      u64 o = __shfl_down(kb, off);
      kb = (o>kb) ? o : kb;
    }
    int par = step & 1;
    if (lane==0) skey[par][wv]=kb;
    __syncthreads();                     // single barrier per step
    u64 km = skey[par][0];
    #pragma unroll
    for (int w=1;w<8;w++){
      u64 o = skey[par][w];
      km = (o>km) ? o : km;
    }
    far = (int)(0xFFFFFFFFu - (u32)(km & 0xFFFFFFFFull));
  }
  // f32 output: exact raw coordinates of selected points
  for (int i=tid;i<M_;i+=512){
    int id = sidx[i];
    float x=sx[id], y=sy[id], z=sz[id];
    size_t o=(size_t)(b*M_+i)*3;
    nxyz[o]=x; nxyz[o+1]=y; nxyz[o+2]=z;
    out0[o]=x; out0[o+1]=y; out0[o+2]=z;
  }
}

// ---------------------------------------------------------------- ball query
#define BQCAP 512
__global__ __launch_bounds__(512) void k_bq(const float* __restrict__ xyz, const float* __restrict__ nxyz,
                                            int* __restrict__ knn)
{
  __shared__ float4 sP[N_];
  __shared__ float candd[8][BQCAP];
  __shared__ u16  candi[8][BQCAP];
  int tid=threadIdx.x;
  int cid0 = blockIdx.x*8;
  int b = cid0 >> 11;
  const float* xp = xyz + (size_t)b*N_*3;
  for (int i=tid;i<N_;i+=512){
    float x=xp[i*3], y=xp[i*3+1], z=xp[i*3+2];
    float x2 = __fmul_rn(x,x);
    x2 = __fadd_rn(x2, __fmul_rn(y,y));
    x2 = __fadd_rn(x2, __fmul_rn(z,z));
    sP[i]=make_float4(x,y,z,x2);
  }
  __syncthreads();
  int w=tid>>6, lane=tid&63;
  int cid = cid0 + w;
  float cx=nxyz[(size_t)cid*3], cy=nxyz[(size_t)cid*3+1], cz=nxyz[(size_t)cid*3+2];
  float c2 = __fmul_rn(cx,cx);
  c2 = __fadd_rn(c2, __fmul_rn(cy,cy));
  c2 = __fadd_rn(c2, __fmul_rn(cz,cz));
  int cnt=0;
  for (int i0=0;i0<N_;i0+=64){
    int i=i0+lane;
    float4 p=sP[i];
    float dot = __fmul_rn(cx,p.x);
    dot = __fadd_rn(dot, __fmul_rn(cy,p.y));
    dot = __fadd_rn(dot, __fmul_rn(cz,p.z));
    float d2 = __fsub_rn(__fadd_rn(c2,p.w), __fmul_rn(2.0f,dot));
    float d = sqrtf(fmaxf(d2,0.f));
    bool in = (d <= 0.4f);
    u64 msk = __ballot(in);
    int pos = cnt + __popcll(msk & ((1ull<<lane)-1ull));
    if (in && pos<BQCAP){ candd[w][pos]=d; candi[w][pos]=(u16)i; }
    cnt += __popcll(msk);
  }
  int R = cnt<BQCAP ? cnt : BQCAP;
  int* kout = knn + (size_t)cid*NS_;
  if (R >= NS_){
    for (int s=0;s<NS_;s++){
      float bvv=3e38f; int bpp=1<<30;
      for (int j=lane;j<R;j+=64){
        float v=candd[w][j];
        if (v<bvv){ bvv=v; bpp=j; }
      }
      #pragma unroll
      for (int off=32;off>0;off>>=1){
        float ov=__shfl_down(bvv,off); int op=__shfl_down(bpp,off);
        if (ov<bvv || (ov==bvv && op<bpp)){ bvv=ov; bpp=op; }
      }
      if (lane==0){ kout[s]=candi[w][bpp]; candd[w][bpp]=3e38f; }
    }
  } else {
    if (lane<R) kout[lane]=candi[w][lane];
    int need = NS_-R, slot = R;
    for (int i0=0; i0<N_ && need>0; i0+=64){
      int i=i0+lane;
      float4 p=sP[i];
      float dot = __fmul_rn(cx,p.x);
      dot = __fadd_rn(dot, __fmul_rn(cy,p.y));
      dot = __fadd_rn(dot, __fmul_rn(cz,p.z));
      float d2 = __fsub_rn(__fadd_rn(c2,p.w), __fmul_rn(2.0f,dot));
      float d = sqrtf(fmaxf(d2,0.f));
      bool in = (d <= 0.4f);
      u64 mm = __ballot(!in);
      while (mm && need>0){
        int bpos = __ffsll((long long)mm)-1;
        if (lane==0) kout[slot] = i0+bpos;
        slot++; need--;
        mm &= mm-1;
      }
    }
  }
}

// ---------------------------------------------------------------- layer 0 (gather+concat fused)
__global__ __launch_bounds__(256) void k_mm0(const float* __restrict__ xyz, const u16* __restrict__ featT,
                                             const int* __restrict__ knn, const float* __restrict__ nxyz,
                                             const float* __restrict__ Wt0, const float* __restrict__ biasf,
                                             u16* __restrict__ Y0)
{
  __shared__ u16 Xs[256*70];
  __shared__ float Wl[67*64];
  int tid=threadIdx.x;
  for (int i=tid;i<67*64;i+=256) Wl[i]=Wt0[i];
  int base = blockIdx.x*256;
  {
    int row = base + tid;
    int bm  = row >> 5;
    int b   = row >> 16;
    int n   = knn[row];
    const float* cp = nxyz + (size_t)bm*3;
    const float* xp = xyz + ((size_t)b*N_ + n)*3;
    u16* xr = &Xs[tid*70];
    xr[0]=f2bf(xp[0]-cp[0]);
    xr[1]=f2bf(xp[1]-cp[1]);
    xr[2]=f2bf(xp[2]-cp[2]);
    const uint4* fp = (const uint4*)(featT + ((size_t)b*N_ + n)*CIN_);
    #pragma unroll
    for (int i=0;i<8;i++){
      uint4 v=fp[i];
      u16* d = xr + 3 + i*8;
      d[0]=(u16)(v.x&0xFFFFu); d[1]=(u16)(v.x>>16);
      d[2]=(u16)(v.y&0xFFFFu); d[3]=(u16)(v.y>>16);
      d[4]=(u16)(v.z&0xFFFFu); d[5]=(u16)(v.z>>16);
      d[6]=(u16)(v.w&0xFFFFu); d[7]=(u16)(v.w>>16);
    }
  }
  __syncthreads();
  int g=tid>>7, rt=tid&127;
  float acc0[32], acc1[32];
  #pragma unroll
  for (int j=0;j<32;j++){ acc0[j]=0.f; acc1[j]=0.f; }
  const u16* xa=&Xs[rt*70];
  const u16* xb=&Xs[(rt+128)*70];
  for (int c=0;c<67;c++){
    float a=bf2f(xa[c]);
    float bx=bf2f(xb[c]);
    const float4* wr=(const float4*)&Wl[c*64 + g*32];
    #pragma unroll
    for (int o=0;o<8;o++){
      float4 wv=wr[o];
      acc0[o*4+0]+=a*wv.x;  acc0[o*4+1]+=a*wv.y;  acc0[o*4+2]+=a*wv.z;  acc0[o*4+3]+=a*wv.w;
      acc1[o*4+0]+=bx*wv.x; acc1[o*4+1]+=bx*wv.y; acc1[o*4+2]+=bx*wv.z; acc1[o*4+3]+=bx*wv.w;
    }
  }
  float bb[32];
  #pragma unroll
  for (int j=0;j<32;j++) bb[j]=biasf[g*32+j];
  u16* y0p = Y0 + ((size_t)(base+rt))*64 + g*32;
  u16* y1p = Y0 + ((size_t)(base+rt+128))*64 + g*32;
  #pragma unroll
  for (int j=0;j<32;j++){
    y0p[j]=f2bf(acc0[j]+bb[j]);
    y1p[j]=f2bf(acc1[j]+bb[j]);
  }
}

// ---------------------------------------------------------------- channel stats (sum, sumsq)
template<int C>
__global__ __launch_bounds__(256) void k_stats(const u16* __restrict__ Y, float* __restrict__ statsOut)
{
  __shared__ float red[512];
  int tid=threadIdx.x;
  int c = tid & (C-1);
  int gp = tid / C;
  const int GPT = 256/C;
  int r0 = blockIdx.x*GPT + gp;
  int stride = gridDim.x*GPT;
  float s=0.f, ss=0.f;
  for (int r=r0; r<ROWS_; r+=stride){
    float v=bf2f(Y[(size_t)r*C + c]);
    s+=v; ss+=v*v;
  }
  red[tid*2]=s; red[tid*2+1]=ss;
  __syncthreads();
  if (tid<C){
    float a=0.f,b2=0.f;
    for (int q=0;q<GPT;q++){ a+=red[(q*C+tid)*2]; b2+=red[(q*C+tid)*2+1]; }
    atomicAdd(&statsOut[tid*2],a);
    atomicAdd(&statsOut[tid*2+1],b2);
  }
}

// ---------------------------------------------------------------- layer 1 (bn0+relu fused into stage; in-place)
__global__ __launch_bounds__(256) void k_mm1(u16* __restrict__ Y, const float* __restrict__ Wt1,
                                             const float* __restrict__ bias1, const float* __restrict__ gf0,
                                             const float* __restrict__ btf0, const float* __restrict__ stats0)
{
  __shared__ u16 Xs[256*66];
  __shared__ float Wl[64*64];
  __shared__ float sc[64], sh[64];
  int tid=threadIdx.x;
  if (tid<64){
    float mu = stats0[tid*2]*INV_ROWS;
    float var= stats0[tid*2+1]*INV_ROWS - mu*mu;
    float rs = 1.0f/sqrtf(var+EPSF);
    float s  = rs*gf0[tid];
    sc[tid]=s; sh[tid]=btf0[tid]-mu*s;
  }
  for (int i=tid;i<64*64;i+=256) Wl[i]=Wt1[i];
  __syncthreads();
  size_t base=(size_t)blockIdx.x*256;
  for (int i=tid;i<2048;i+=256){
    int rl=i>>3, c0=(i&7)*8;
    uint4 v=*(const uint4*)(Y + (base+rl)*64 + c0);
    u32 arr[4]={v.x,v.y,v.z,v.w};
    u16* d=&Xs[rl*66+c0];
    #pragma unroll
    for (int q=0;q<4;q++){
      int cc=c0+q*2;
      float lo=bf2f((u16)(arr[q]&0xFFFFu));
      float hi=bf2f((u16)(arr[q]>>16));
      lo=fmaxf(0.f, lo*sc[cc]+sh[cc]);
      hi=fmaxf(0.f, hi*sc[cc+1]+sh[cc+1]);
      d[q*2]=f2bf(lo); d[q*2+1]=f2bf(hi);
    }
  }
  __syncthreads();
  int g=tid>>7, rt=tid&127;
  float acc0[32], acc1[32];
  #pragma unroll
  for (int j=0;j<32;j++){ acc0[j]=0.f; acc1[j]=0.f; }
  const u16* xa=&Xs[rt*66];
  const u16* xb=&Xs[(rt+128)*66];
  for (int c=0;c<64;c++){
    float a=bf2f(xa[c]);
    float bx=bf2f(xb[c]);
    const float4* wr=(const float4*)&Wl[c*64 + g*32];
    #pragma unroll
    for (int o=0;o<8;o++){
      float4 wv=wr[o];
      acc0[o*4+0]+=a*wv.x;  acc0[o*4+1]+=a*wv.y;  acc0[o*4+2]+=a*wv.z;  acc0[o*4+3]+=a*wv.w;
      acc1[o*4+0]+=bx*wv.x; acc1[o*4+1]+=bx*wv.y; acc1[o*4+2]+=bx*wv.z; acc1[o*4+3]+=bx*wv.w;
    }
  }
  float bb[32];
  #pragma unroll
  for (int j=0;j<32;j++) bb[j]=bias1[g*32+j];
  u16* y0p = Y + (base+rt)*64 + g*32;
  u16* y1p = Y + (base+rt+128)*64 + g*32;
  #pragma unroll
  for (int j=0;j<32;j++){
    y0p[j]=f2bf(acc0[j]+bb[j]);
    y1p[j]=f2bf(acc1[j]+bb[j]);
  }
}

// ---------------------------------------------------------------- layer 2: stats + RAW maxpool (Y2 never stored)
// BN2+ReLU is monotone non-decreasing per channel (gamma>0, rsqrt>0), and f32 rounding
// preserves monotonicity => max_k relu(sc*x+sh) == relu(sc*max_k(x)+sh) bit-for-bit.
// So this pass computes channel stats AND the raw pre-BN maxpool (written to out1);
// k_pool applies the affine+relu afterwards.
__global__ __launch_bounds__(256) void k_mm2a(const u16* __restrict__ Y1, const float* __restrict__ Wt2,
                                              const float* __restrict__ bias2, const float* __restrict__ gf1,
                                              const float* __restrict__ btf1, const float* __restrict__ stats1,
                                              float* __restrict__ stats2, float* __restrict__ out1)
{
  __shared__ u16 Xs[128*66];
  __shared__ float Wl[64*128];
  __shared__ float sc[64], sh[64];
  __shared__ float res[4][128];
  int tid=threadIdx.x;
  if (tid<64){
    float mu = stats1[tid*2]*INV_ROWS;
    float var= stats1[tid*2+1]*INV_ROWS - mu*mu;
    float rs = 1.0f/sqrtf(var+EPSF);
    float s  = rs*gf1[tid];
    sc[tid]=s; sh[tid]=btf1[tid]-mu*s;
  }
  for (int i=tid;i<64*128;i+=256) Wl[i]=Wt2[i];
  int g=tid>>6, rt=tid&63;
  float bb[32];
  #pragma unroll
  for (int j=0;j<32;j++) bb[j]=bias2[g*32+j];
  float sSum[32], sSq[32];
  #pragma unroll
  for (int j=0;j<32;j++){ sSum[j]=0.f; sSq[j]=0.f; }
  __syncthreads();
  for (int tile=blockIdx.x; tile<4096; tile+=gridDim.x){
    size_t base=(size_t)tile*128;
    for (int i=tid;i<1024;i+=256){
      int rl=i>>3, c0=(i&7)*8;
      uint4 v=*(const uint4*)(Y1 + (base+rl)*64 + c0);
      u32 arr[4]={v.x,v.y,v.z,v.w};
      u16* d=&Xs[rl*66+c0];
      #pragma unroll
      for (int q=0;q<4;q++){
        int cc=c0+q*2;
        float lo=bf2f((u16)(arr[q]&0xFFFFu));
        float hi=bf2f((u16)(arr[q]>>16));
        lo=fmaxf(0.f, lo*sc[cc]+sh[cc]);
        hi=fmaxf(0.f, hi*sc[cc+1]+sh[cc+1]);
        d[q*2]=f2bf(lo); d[q*2+1]=f2bf(hi);
      }
    }
    __syncthreads();
    float acc0[32], acc1[32];
    #pragma unroll
    for (int j=0;j<32;j++){ acc0[j]=0.f; acc1[j]=0.f; }
    const u16* xa=&Xs[rt*66];
    const u16* xb=&Xs[(rt+64)*66];
    for (int c=0;c<64;c++){
      float a=bf2f(xa[c]);
      float bx=bf2f(xb[c]);
      const float4* wr=(const float4*)&Wl[c*128 + g*32];
      #pragma unroll
      for (int o=0;o<8;o++){
        float4 wv=wr[o];
        acc0[o*4+0]+=a*wv.x;  acc0[o*4+1]+=a*wv.y;  acc0[o*4+2]+=a*wv.z;  acc0[o*4+3]+=a*wv.w;
        acc1[o*4+0]+=bx*wv.x; acc1[o*4+1]+=bx*wv.y; acc1[o*4+2]+=bx*wv.z; acc1[o*4+3]+=bx*wv.w;
      }
    }
    // stats + raw maxpool over k (lanes rt&31 = k; rt<32: centroid0, rt>=32: centroid1 of acc0;
    // acc1 covers centroids 2,3)
    #pragma unroll
    for (int j=0;j<32;j++){
      float y0=acc0[j]+bb[j], y1=acc1[j]+bb[j];
      sSum[j]+=y0+y1;
      sSq[j] +=y0*y0+y1*y1;
      float a=y0, b2=y1;
      #pragma unroll
      for (int off=16;off>0;off>>=1){
        a = fmaxf(a, __shfl_down(a, off, 32));
        b2= fmaxf(b2,__shfl_down(b2,off, 32));
      }
      if ((rt&31)==0){
        int o=g*32+j;
        res[rt>>5][o]     = a;
        res[2+(rt>>5)][o] = b2;
      }
    }
    __syncthreads();
    int bm0 = tile*4;
    for (int e=tid;e<512;e+=256){
      int gr=e>>7, o=e&127;
      int bm=bm0+gr; int bi=bm>>11, m=bm&2047;
      out1[((size_t)bi*128+o)*M_ + m] = res[gr][o];
    }
    __syncthreads();
  }
  #pragma unroll
  for (int off=32;off>0;off>>=1){
    #pragma unroll
    for (int j=0;j<32;j++){
      sSum[j]+=__shfl_down(sSum[j],off);
      sSq[j] +=__shfl_down(sSq[j],off);
    }
  }
  if (rt==0){
    #pragma unroll
    for (int j=0;j<32;j++){
      atomicAdd(&stats2[(g*32+j)*2],  sSum[j]);
      atomicAdd(&stats2[(g*32+j)*2+1],sSq[j]);
    }
  }
}

// ---------------------------------------------------------------- final pool: in-place BN2+ReLU on raw maxes
__global__ __launch_bounds__(256) void k_pool(float* __restrict__ out1, const float* __restrict__ stats2,
                                              const float* __restrict__ gf2, const float* __restrict__ btf2)
{
  int idx = blockIdx.x*256 + threadIdx.x;     // 8*128*2048 = 2097152 elements
  int o = (idx >> 11) & 127;
  float mu = stats2[o*2]*INV_ROWS;
  float var= stats2[o*2+1]*INV_ROWS - mu*mu;
  float rs = 1.0f/sqrtf(var+EPSF);
  float s  = rs*gf2[o];
  float sh = btf2[o]-mu*s;
  out1[idx] = fmaxf(0.f, out1[idx]*s + sh);
}

// ---------------------------------------------------------------- launch
extern "C" void kernel_launch(void* const* d_in, const int* in_sizes, int n_in,
                              void* d_out, int out_size, void* d_ws, size_t ws_size,
                              hipStream_t stream)
{
  (void)in_sizes; (void)n_in; (void)out_size; (void)ws_size;
  const float* xyz =(const float*)d_in[0];
  const float* feat=(const float*)d_in[1];
  const float* w0=(const float*)d_in[2],  *b0=(const float*)d_in[3],  *g0=(const float*)d_in[4],  *bt0=(const float*)d_in[5];
  const float* w1=(const float*)d_in[6],  *b1=(const float*)d_in[7],  *g1=(const float*)d_in[8],  *bt1=(const float*)d_in[9];
  const float* w2=(const float*)d_in[10], *b2=(const float*)d_in[11], *g2=(const float*)d_in[12], *bt2=(const float*)d_in[13];
  float* out0=(float*)d_out;
  float* out1=out0 + (size_t)B_*M_*3;

  char* ws=(char*)d_ws;
  float* nxyz =(float*)(ws);              // 196608 B
  int*   knn  =(int*)  (ws + 262144);     // 2097152
  float* Wt0  =(float*)(ws + 2359296);    // 17408
  float* Wt1  =(float*)(ws + 2376704);    // 16384
  float* Wt2  =(float*)(ws + 2393088);    // 32768
  float* biasf=(float*)(ws + 2425856);    // 1536
  float* gfp  =(float*)(ws + 2427392);    // 1536
  float* btfp =(float*)(ws + 2428928);    // 1536
  float* stats=(float*)(ws + 2430464);    // 3072
  u16*   featT=(u16*)  (ws + 2433536);    // 8388608
  u16*   Y0   =(u16*)  (ws + 10822144);   // 67108864  (total ~78 MB)

  k_prep<<<1,256,0,stream>>>(w0,b0,g0,bt0,w1,b1,g1,bt1,w2,b2,g2,bt2,Wt0,Wt1,Wt2,biasf,gfp,btfp,stats);
  k_tr<<<dim3(128,8),256,0,stream>>>(feat, featT);
  k_fps<<<B_,512,0,stream>>>(xyz, nxyz, out0);
  k_bq<<<2048,512,0,stream>>>(xyz, nxyz, knn);
  k_mm0<<<2048,256,0,stream>>>(xyz, featT, knn, nxyz, Wt0, biasf+0, Y0);
  k_stats<64><<<512,256,0,stream>>>(Y0, stats+0);
  k_mm1<<<2048,256,0,stream>>>(Y0, Wt1, biasf+128, gfp+0, btfp+0, stats+0);
  k_stats<64><<<512,256,0,stream>>>(Y0, stats+256);
  k_mm2a<<<512,256,0,stream>>>(Y0, Wt2, biasf+256, gfp+128, btfp+128, stats+256, stats+512, out1);
  k_pool<<<8192,256,0,stream>>>(out1, stats+512, gfp+256, btfp+256);
}